// Round 1
// baseline (153.632 us; speedup 1.0000x reference)
//
#include <hip/hip_runtime.h>

#define N_NODES_C   524288
#define N_EDGES_C   786432
#define NUM_GRAPHS_C 8192
#define NT 16          // NUM_NODE_TYPES
#define NODE_DIM_C 256
#define EDGE_DIM_C 128
#define HDIM 384       // NODE_DIM + EDGE_DIM
#define KC 48          // folded inner dim: 16 (node) + 32 (edge)

// R11 grid layout: edge/node roles interleaved so both phases are co-resident
// on every CU (latency-bound gather hides under BW-bound node stream).
// Role bit must be ABOVE the XCD round-robin bits (XCD = blk % 8), else one
// role pins to even XCDs: role = (blk>>3)&1, pair index v = (blk>>4)*8 + (blk&7).
#define PAIR_BLOCKS  4096          // 2048 edge-role + 2048 node-role, 4 graphs each
#define FOLD_BLOCKS  72            // ceil(KC*HDIM / 256), dispatched last
#define FOLD_BASE    PAIR_BLOCKS
#define TOTAL_BLOCKS (PAIR_BLOCKS + FOLD_BLOCKS)

// ---------------- workspace layout (bytes) ----------------
#define WS_NM    0                  // float[8192*16]   (node means)
#define WS_EM    524288             // float[8192*32]   (edge means)
#define WS_WC    1572864            // float[48*384]    (folded weights)

__device__ __forceinline__ int lower_bound_i32(const int* __restrict__ a, int n, int key) {
    int lo = 0, hi = n;
    while (lo < hi) {
        int mid = (lo + hi) >> 1;
        if (a[mid] < key) lo = mid + 1; else hi = mid;
    }
    return lo;
}

// In-wave segment bounds: lanes 0-31 chase start(g), lanes 32-63 chase end(g)
// concurrently, then shuffle-broadcast.
__device__ __forceinline__ void wave_seg_bounds(const int* __restrict__ b, int n,
                                                int g, int lane, int& s, int& e) {
    int key = g + ((lane >= 32) ? 1 : 0);
    int lo = lower_bound_i32(b, n, key);
    s = __shfl(lo, 0, 64);
    e = __shfl(lo, 32, 64);
}

__device__ __forceinline__ void f4_add(float4& a, const float4 v) {
    a.x += v.x; a.y += v.y; a.z += v.z; a.w += v.w;
}

__device__ __forceinline__ void f4_shfl_xor_add(float4& a, int mask) {
    a.x += __shfl_xor(a.x, mask, 64);
    a.y += __shfl_xor(a.y, mask, 64);
    a.z += __shfl_xor(a.z, mask, 64);
    a.w += __shfl_xor(a.w, mask, 64);
}

// KM mega-kernel (R11: interleaved roles + deep-pipelined edge gather):
//  blocks [0,4096): role=(blk>>3)&1 → 0: edge means, 1: node means; 4 graphs/blk.
//  blocks [4096,+72): Wc[k][j] = embedder_row(k) . W1 block (unroll 16).
//  Edge loop: lane = eo(0..7)*8 + p*4 + quad (quad shares a 64-B row, 16 rows
//  per instr, each line requested once). 4 streams at j, j+8, j+16, j+24,
//  stride 32; indices prefetched 1 iter ahead of the row loads, row loads
//  prefetched 1 iter ahead of the accumulate → ~8 vmem instrs in flight/wave
//  (vs 2 before). Loads predicated+zero-filled so trip count is wave-uniform.
__global__ __launch_bounds__(256) void km_mega(
    const float* __restrict__ h_node,
    const int* __restrict__ bnode, const int* __restrict__ bedge,
    const int* __restrict__ esrc, const int* __restrict__ edst,
    const float* __restrict__ Wn, const float* __restrict__ We,
    const float* __restrict__ W1,
    float* __restrict__ nm, float* __restrict__ em, float* __restrict__ Wc) {
    int blk  = blockIdx.x;
    int wave = threadIdx.x >> 6;
    int lane = threadIdx.x & 63;
    const float4* h4 = (const float4*)h_node;

    if (blk >= FOLD_BASE) {
        // ---- weight fold ----
        int o = (blk - FOLD_BASE) * 256 + threadIdx.x;   // 0..18431 (= KC*HDIM)
        if (o >= KC * HDIM) return;
        int k = o / HDIM, j = o % HDIM;
        float acc = 0.f;
        if (k < NT) {
            const float* wr = &Wn[k * NODE_DIM_C];
            #pragma unroll 16
            for (int kk = 0; kk < NODE_DIM_C; ++kk)
                acc = fmaf(wr[kk], W1[(size_t)kk * HDIM + j], acc);
        } else {
            const float* wr = &We[(k - NT) * EDGE_DIM_C];
            #pragma unroll 16
            for (int kk = 0; kk < EDGE_DIM_C; ++kk)
                acc = fmaf(wr[kk], W1[(size_t)(NODE_DIM_C + kk) * HDIM + j], acc);
        }
        Wc[o] = acc;
        return;
    }

    int role = (blk >> 3) & 1;                  // above XCD bits: both roles on every XCD
    int v    = ((blk >> 4) << 3) | (blk & 7);   // 0..2047
    int g    = v * 4 + wave;

    if (role == 0) {
        // ---- edge means (deep-pipelined 4-stream gather) ----
        int s, e;
        wave_seg_bounds(bedge, N_EDGES_C, g, lane, s, e);
        int eo   = lane >> 3;          // 0..7 edge slot
        int p    = (lane >> 2) & 1;    // 0=src 1=dst
        int quad = lane & 3;           // 16 B quarter of the 64-B row
        const int* __restrict__ idxp = p ? edst : esrc;
        const float4 z4 = make_float4(0.f, 0.f, 0.f, 0.f);
        float4 a0 = z4, a1 = z4, a2 = z4, a3 = z4;

        int cnt = e - s;
        int T = (cnt + 31) >> 5;       // wave-uniform trip count (stride 32)
        int j0 = s + eo, j1 = j0 + 8, j2 = j0 + 16, j3 = j0 + 24;

        // prologue: idx(iter0) -> rows(iter0) -> idx(iter1)
        int n0 = (j0 < e) ? idxp[j0] : -1;
        int n1 = (j1 < e) ? idxp[j1] : -1;
        int n2 = (j2 < e) ? idxp[j2] : -1;
        int n3 = (j3 < e) ? idxp[j3] : -1;
        int m0 = (j0 + 32 < e) ? idxp[j0 + 32] : -1;
        int m1 = (j1 + 32 < e) ? idxp[j1 + 32] : -1;
        int m2 = (j2 + 32 < e) ? idxp[j2 + 32] : -1;
        int m3 = (j3 + 32 < e) ? idxp[j3 + 32] : -1;
        float4 v0 = (n0 >= 0) ? h4[(size_t)n0 * 4 + quad] : z4;
        float4 v1 = (n1 >= 0) ? h4[(size_t)n1 * 4 + quad] : z4;
        float4 v2 = (n2 >= 0) ? h4[(size_t)n2 * 4 + quad] : z4;
        float4 v3 = (n3 >= 0) ? h4[(size_t)n3 * 4 + quad] : z4;

        for (int t = 1; t < T; ++t) {
            j0 += 32; j1 += 32; j2 += 32; j3 += 32;
            // idx for iter t+1 (independent, issues first)
            int q0 = (j0 + 32 < e) ? idxp[j0 + 32] : -1;
            int q1 = (j1 + 32 < e) ? idxp[j1 + 32] : -1;
            int q2 = (j2 + 32 < e) ? idxp[j2 + 32] : -1;
            int q3 = (j3 + 32 < e) ? idxp[j3 + 32] : -1;
            // rows for iter t (idx prefetched last iter, already arrived)
            float4 w0 = (m0 >= 0) ? h4[(size_t)m0 * 4 + quad] : z4;
            float4 w1 = (m1 >= 0) ? h4[(size_t)m1 * 4 + quad] : z4;
            float4 w2 = (m2 >= 0) ? h4[(size_t)m2 * 4 + quad] : z4;
            float4 w3 = (m3 >= 0) ? h4[(size_t)m3 * 4 + quad] : z4;
            // accumulate rows of iter t-1 (issued last iter → 1 full iter of hiding)
            f4_add(a0, v0); f4_add(a1, v1); f4_add(a2, v2); f4_add(a3, v3);
            v0 = w0; v1 = w1; v2 = w2; v3 = w3;
            m0 = q0; m1 = q1; m2 = q2; m3 = q3;
        }
        // last iteration's rows (predicated lanes contributed exact zeros)
        f4_add(a0, v0); f4_add(a1, v1); f4_add(a2, v2); f4_add(a3, v3);
        f4_add(a0, a1); f4_add(a2, a3); f4_add(a0, a2);
        // reduce over eo (lane bits 3..5)
        f4_shfl_xor_add(a0, 8);
        f4_shfl_xor_add(a0, 16);
        f4_shfl_xor_add(a0, 32);
        if (eo == 0) {
            float inv = 1.f / fmaxf((float)cnt, 1.f);
            // em row = 32 floats: quads 0..3 = src half, 4..7 = dst half
            ((float4*)em)[(size_t)g * 8 + p * 4 + quad] =
                make_float4(a0.x * inv, a0.y * inv, a0.z * inv, a0.w * inv);
        }
    } else {
        // ---- node means (streaming, unchanged structure) ----
        int s, e;
        wave_seg_bounds(bnode, N_NODES_C, g, lane, s, e);
        int row_off = lane >> 2;   // 0..15
        int quad    = lane & 3;    // 0..3
        float4 a0 = make_float4(0.f, 0.f, 0.f, 0.f);
        float4 a1 = a0;
        int i = s + row_off;
        for (; i + 16 < e; i += 32) {
            float4 v0 = h4[(size_t)i * 4 + quad];
            float4 v1 = h4[(size_t)(i + 16) * 4 + quad];
            f4_add(a0, v0);
            f4_add(a1, v1);
        }
        if (i < e) f4_add(a0, h4[(size_t)i * 4 + quad]);
        f4_add(a0, a1);
        f4_shfl_xor_add(a0, 4);
        f4_shfl_xor_add(a0, 8);
        f4_shfl_xor_add(a0, 16);
        f4_shfl_xor_add(a0, 32);
        if (row_off == 0) {
            float inv = 1.f / fmaxf((float)(e - s), 1.f);
            ((float4*)nm)[(size_t)g * 4 + quad] =
                make_float4(a0.x * inv, a0.y * inv, a0.z * inv, a0.w * inv);
        }
    }
}

// K3: fused MLP.  pred[g] = relu(f[g] @ Wc + b1) . W2 + b2,  f = [nm | em] (48)
// 384 threads (thread owns column j of Wc in registers), 16 graphs / block.
#define GPB 16
__global__ __launch_bounds__(HDIM) void k3_mlp(
    const float* __restrict__ nm, const float* __restrict__ em,
    const float* __restrict__ Wc, const float* __restrict__ b1,
    const float* __restrict__ W2, const float* __restrict__ b2,
    float* __restrict__ pred) {
    int j = threadIdx.x;
    float wc[KC];
    #pragma unroll
    for (int k = 0; k < KC; ++k) wc[k] = Wc[k * HDIM + j];
    float b1j = b1[j], w2j = W2[j], b20 = b2[0];

    __shared__ float fs[GPB][KC];
    __shared__ float part[GPB][6];
    int g0 = blockIdx.x * GPB;
    #pragma unroll
    for (int t = j; t < GPB * KC; t += HDIM) {
        int g = t / KC, k = t % KC;
        fs[g][k] = (k < NT) ? nm[(size_t)(g0 + g) * NT + k]
                            : em[(size_t)(g0 + g) * 32 + (k - NT)];
    }
    __syncthreads();

    int wave = j >> 6, lane = j & 63;
    for (int g = 0; g < GPB; ++g) {
        float z = b1j;
        #pragma unroll
        for (int k = 0; k < KC; ++k) z = fmaf(fs[g][k], wc[k], z);
        z = fmaxf(z, 0.f);
        float p = z * w2j;
        #pragma unroll
        for (int off = 32; off > 0; off >>= 1) p += __shfl_down(p, off, 64);
        if (lane == 0) part[g][wave] = p;
    }
    __syncthreads();
    if (j < GPB) {
        float sacc = b20;
        #pragma unroll
        for (int w = 0; w < 6; ++w) sacc += part[j][w];
        pred[g0 + j] = sacc;
    }
}

extern "C" void kernel_launch(void* const* d_in, const int* in_sizes, int n_in,
                              void* d_out, int out_size, void* d_ws, size_t ws_size,
                              hipStream_t stream) {
    const float* h_node     = (const float*)d_in[0];
    // d_in[1] = pos_node (unused)
    const int*   batch_node = (const int*)d_in[2];
    const int*   edge_index = (const int*)d_in[3];   // [2, E] row-major
    const int*   batch_edge = (const int*)d_in[4];
    const float* W_node     = (const float*)d_in[5];
    const float* W_edge     = (const float*)d_in[6];
    const float* W1         = (const float*)d_in[7];
    const float* b1         = (const float*)d_in[8];
    const float* W2         = (const float*)d_in[9];
    const float* b2         = (const float*)d_in[10];
    float* pred = (float*)d_out;

    char* ws = (char*)d_ws;
    float* nm = (float*)(ws + WS_NM);
    float* em = (float*)(ws + WS_EM);
    float* Wc = (float*)(ws + WS_WC);

    const int* esrc = edge_index;
    const int* edst = edge_index + N_EDGES_C;

    // KM: interleaved edge/node means (4096) + fold (72); bounds searched in-wave
    km_mega<<<TOTAL_BLOCKS, 256, 0, stream>>>(
        h_node, batch_node, batch_edge, esrc, edst, W_node, W_edge, W1, nm, em, Wc);
    // K3: fused folded MLP
    k3_mlp<<<NUM_GRAPHS_C / GPB, HDIM, 0, stream>>>(nm, em, Wc, b1, W2, b2, pred);
}